// Round 11
// baseline (50.871 us; speedup 1.0000x reference)
//
#include <hip/hip_runtime.h>
#include <math.h>

// Problem constants
constexpr int Bn = 512;
constexpr int Tn = 512;
constexpr int Dn = 128;
constexpr int Hn = 128;
constexpr int NT = 512;       // threads per block (one block per batch)
constexpr int NW = NT / 64;   // 8 waves

// Sum across the 16-lane row group via DPP row rotations (pure VALU, no LDS).
__device__ __forceinline__ float rowsum16(float x) {
    int v;
    v = __float_as_int(x);
    x += __int_as_float(__builtin_amdgcn_update_dpp(0, v, 0x121, 0xF, 0xF, true)); // row_ror:1
    v = __float_as_int(x);
    x += __int_as_float(__builtin_amdgcn_update_dpp(0, v, 0x122, 0xF, 0xF, true)); // row_ror:2
    v = __float_as_int(x);
    x += __int_as_float(__builtin_amdgcn_update_dpp(0, v, 0x124, 0xF, 0xF, true)); // row_ror:4
    v = __float_as_int(x);
    x += __int_as_float(__builtin_amdgcn_update_dpp(0, v, 0x128, 0xF, 0xF, true)); // row_ror:8
    return x;
}

__global__ __launch_bounds__(NT, 4)   // VGPR<=128, 2 blocks/CU — proven spill-free regime
void single_attn_pipe(const float* __restrict__ input,   // [B,T,D]
                      const int*   __restrict__ mask,    // [B,T]
                      const float* __restrict__ Wt,      // [D,H]
                      const float* __restrict__ Wx,      // [D,H]
                      const float* __restrict__ rate,    // [1]
                      float* __restrict__ out_v,         // [B,D]
                      float* __restrict__ out_a)         // [B,T]
{
    const int b    = blockIdx.x;
    const int tid  = threadIdx.x;
    const int lane = tid & 63;
    const int wid  = tid >> 6;
    const int seg  = tid & 15;     // 16 lanes per row; floats seg*8..seg*8+7
    const int rg   = tid >> 4;     // row group 0..31
    const float* __restrict__ inb = input + (size_t)b * Tn * Dn;
    const float4* __restrict__ in4 = (const float4*)inb;

    __shared__ float ps[Tn];          // 2 KB unnormalized weights
    __shared__ int   msk[Tn];         // 2 KB
    __shared__ float lv[Dn];
    __shared__ float qs[Hn];
    __shared__ float us[Dn];
    __shared__ float redl[NW];
    __shared__ int   ired[NW];
    __shared__ float vp[32 * 132];    // 16.9 KB v partials

    // ---- stream-A/B initial loads issued FIRST: overlap the whole prologue ----
    float4 a0 = in4[rg * 32 + seg * 2];
    float4 a1 = in4[rg * 32 + seg * 2 + 1];
    float4 b0 = in4[(256 + rg) * 32 + seg * 2];
    float4 b1 = in4[(256 + rg) * 32 + seg * 2 + 1];

    // ---- prologue: last_idx, lv, q = lv@Wt, u = Wx@q ----
    const int mv = mask[(size_t)b * Tn + tid];
    msk[tid] = mv;
    {
        int ms = mv;
        #pragma unroll
        for (int off = 32; off > 0; off >>= 1) ms += __shfl_down(ms, off, 64);
        if (lane == 0) ired[wid] = ms;
    }
    __syncthreads();
    int last_idx;
    {
        int s = 0;
        #pragma unroll
        for (int w = 0; w < NW; ++w) s += ired[w];
        last_idx = s - 1;
    }
    if (tid < Dn) lv[tid] = inb[(size_t)last_idx * Dn + tid];
    __syncthreads();
    if (tid < Hn) {
        float q0 = 0.f, q1 = 0.f;
        #pragma unroll 16
        for (int d0 = 0; d0 < Dn; d0 += 2) {
            q0 = fmaf(lv[d0],     Wt[d0 * Hn + tid],       q0);
            q1 = fmaf(lv[d0 + 1], Wt[(d0 + 1) * Hn + tid], q1);
        }
        qs[tid] = q0 + q1;
    }
    __syncthreads();
    if (tid < Dn) {
        float t0 = 0.f, t1 = 0.f;
        const float* wxr = Wx + tid * Hn;
        #pragma unroll 16
        for (int h = 0; h < Hn; h += 2) {
            t0 = fmaf(wxr[h],     qs[h],     t0);
            t1 = fmaf(wxr[h + 1], qs[h + 1], t1);
        }
        us[tid] = t0 + t1;
    }
    __syncthreads();

    const float srate = 1.f / (1.f + __expf(-rate[0]));
    const float4 u4a = ((const float4*)us)[seg * 2];
    const float4 u4b = ((const float4*)us)[seg * 2 + 1];

    // ---- fused streaming pass, software-pipelined (1-ahead, 2 streams) ----
    // e = relu(sig/den) in [0, ~1.45] (den >= sigmoid(0.8)*log(2.72) ~= 0.69),
    // so exp(e) <= 4.3: softmax needs no max subtraction.
    float4 vA0 = make_float4(0.f, 0.f, 0.f, 0.f);
    float4 vA1 = make_float4(0.f, 0.f, 0.f, 0.f);
    float4 vB0 = make_float4(0.f, 0.f, 0.f, 0.f);
    float4 vB1 = make_float4(0.f, 0.f, 0.f, 0.f);
    float  lsum = 0.f;

    #pragma unroll
    for (int it = 0; it < 8; ++it) {
        float4 na0, na1, nb0, nb1;
        if (it < 7) {                              // prefetch next iteration (both streams)
            const int ra = (it + 1) * 32 + rg;
            const int rb = 256 + ra;
            na0 = in4[ra * 32 + seg * 2];
            na1 = in4[ra * 32 + seg * 2 + 1];
            nb0 = in4[rb * 32 + seg * 2];
            nb1 = in4[rb * 32 + seg * 2 + 1];
        }
        // ---- stream A: row = it*32+rg ----
        {
            const int row = it * 32 + rg;
            float dot = a0.x * u4a.x + a0.y * u4a.y + a0.z * u4a.z + a0.w * u4a.w;
            dot = fmaf(a1.x, u4b.x, dot);
            dot = fmaf(a1.y, u4b.y, dot);
            dot = fmaf(a1.z, u4b.z, dot);
            dot = fmaf(a1.w, u4b.w, dot);
            dot = rowsum16(dot);
            const float sig = 1.f / (1.f + __expf(-dot));
            const float den = srate * (__logf(2.72f + (1.f - sig)) * (float)(Tn - row));
            const float e   = fmaxf(sig / den, 0.f);
            const float p   = msk[row] ? __expf(e) : 0.f;
            vA0.x = fmaf(p, a0.x, vA0.x);
            vA0.y = fmaf(p, a0.y, vA0.y);
            vA0.z = fmaf(p, a0.z, vA0.z);
            vA0.w = fmaf(p, a0.w, vA0.w);
            vA1.x = fmaf(p, a1.x, vA1.x);
            vA1.y = fmaf(p, a1.y, vA1.y);
            vA1.z = fmaf(p, a1.z, vA1.z);
            vA1.w = fmaf(p, a1.w, vA1.w);
            if (seg == 0) { ps[row] = p; lsum += p; }
        }
        // ---- stream B: row = 256 + it*32+rg ----
        {
            const int row = 256 + it * 32 + rg;
            float dot = b0.x * u4a.x + b0.y * u4a.y + b0.z * u4a.z + b0.w * u4a.w;
            dot = fmaf(b1.x, u4b.x, dot);
            dot = fmaf(b1.y, u4b.y, dot);
            dot = fmaf(b1.z, u4b.z, dot);
            dot = fmaf(b1.w, u4b.w, dot);
            dot = rowsum16(dot);
            const float sig = 1.f / (1.f + __expf(-dot));
            const float den = srate * (__logf(2.72f + (1.f - sig)) * (float)(Tn - row));
            const float e   = fmaxf(sig / den, 0.f);
            const float p   = msk[row] ? __expf(e) : 0.f;
            vB0.x = fmaf(p, b0.x, vB0.x);
            vB0.y = fmaf(p, b0.y, vB0.y);
            vB0.z = fmaf(p, b0.z, vB0.z);
            vB0.w = fmaf(p, b0.w, vB0.w);
            vB1.x = fmaf(p, b1.x, vB1.x);
            vB1.y = fmaf(p, b1.y, vB1.y);
            vB1.z = fmaf(p, b1.z, vB1.z);
            vB1.w = fmaf(p, b1.w, vB1.w);
            if (seg == 0) { ps[row] = p; lsum += p; }
        }
        if (it < 7) { a0 = na0; a1 = na1; b0 = nb0; b1 = nb1; }
    }

    // merge streams, stash v partials (16B-aligned: rg*132 + seg*8)
    {
        float4 v0 = make_float4(vA0.x + vB0.x, vA0.y + vB0.y, vA0.z + vB0.z, vA0.w + vB0.w);
        float4 v1 = make_float4(vA1.x + vB1.x, vA1.y + vB1.y, vA1.z + vB1.z, vA1.w + vB1.w);
        float* vr = vp + rg * 132 + seg * 8;
        ((float4*)vr)[0] = v0;
        ((float4*)vr)[1] = v1;
    }
    // block-reduce l (nonzero only on seg==0 lanes)
    float ls = lsum;
    #pragma unroll
    for (int off = 32; off > 0; off >>= 1) ls += __shfl_down(ls, off, 64);
    if (lane == 0) redl[wid] = ls;
    __syncthreads();   // vp + ps + redl visible

    float l = 0.f;
    #pragma unroll
    for (int w = 0; w < NW; ++w) l += redl[w];
    const float inv_l = 1.f / l;

    out_a[(size_t)b * Tn + tid] = ps[tid] * inv_l;

    if (tid < Dn) {
        float s = 0.f;
        #pragma unroll
        for (int r = 0; r < 32; ++r) s += vp[r * 132 + tid];
        out_v[(size_t)b * Dn + tid] = s * inv_l;
    }
}

extern "C" void kernel_launch(void* const* d_in, const int* in_sizes, int n_in,
                              void* d_out, int out_size, void* d_ws, size_t ws_size,
                              hipStream_t stream) {
    const float* input = (const float*)d_in[0];   // [B,T,D]
    const int*   mask  = (const int*)d_in[1];     // [B,T]
    const float* Wt    = (const float*)d_in[2];   // [D,H]
    const float* Wx    = (const float*)d_in[3];   // [D,H]
    const float* rate  = (const float*)d_in[4];   // [1]

    float* out   = (float*)d_out;
    float* out_v = out;                 // [B,D]  (return order: v, a)
    float* out_a = out + Bn * Dn;       // [B,T]

    single_attn_pipe<<<Bn, NT, 0, stream>>>(input, mask, Wt, Wx, rate, out_v, out_a);
}

// Round 12
// 37.605 us; speedup vs baseline: 1.3528x; 1.3528x over previous
//
#include <hip/hip_runtime.h>
#include <math.h>

// Problem constants
constexpr int Bn = 512;
constexpr int Tn = 512;
constexpr int Dn = 128;
constexpr int Hn = 128;

// Sum across the 16-lane row group via DPP row rotations (pure VALU, no LDS).
__device__ __forceinline__ float rowsum16(float x) {
    int v;
    v = __float_as_int(x);
    x += __int_as_float(__builtin_amdgcn_update_dpp(0, v, 0x121, 0xF, 0xF, true)); // row_ror:1
    v = __float_as_int(x);
    x += __int_as_float(__builtin_amdgcn_update_dpp(0, v, 0x122, 0xF, 0xF, true)); // row_ror:2
    v = __float_as_int(x);
    x += __int_as_float(__builtin_amdgcn_update_dpp(0, v, 0x124, 0xF, 0xF, true)); // row_ror:4
    v = __float_as_int(x);
    x += __int_as_float(__builtin_amdgcn_update_dpp(0, v, 0x128, 0xF, 0xF, true)); // row_ror:8
    return x;
}

// ---------------- K1: u[b] = Wx * (Wt^T * last_visit[b]) ----------------
__global__ __launch_bounds__(128)
void compute_u_kernel(const float* __restrict__ input,   // [B,T,D]
                      const int*   __restrict__ mask,    // [B,T]
                      const float* __restrict__ Wt,      // [D,H]
                      const float* __restrict__ Wx,      // [D,H]
                      float* __restrict__ ws_u)          // [B,D]
{
    const int b   = blockIdx.x;
    const int tid = threadIdx.x;            // 0..127
    const float* __restrict__ inb = input + (size_t)b * Tn * Dn;

    __shared__ float lvs[Dn];
    __shared__ float qs[Hn];
    __shared__ int   ired[2];

    const int4 m4 = ((const int4*)(mask + (size_t)b * Tn))[tid];
    int ms = m4.x + m4.y + m4.z + m4.w;
    #pragma unroll
    for (int off = 32; off > 0; off >>= 1) ms += __shfl_down(ms, off, 64);
    if ((tid & 63) == 0) ired[tid >> 6] = ms;
    __syncthreads();
    const int last_idx = ired[0] + ired[1] - 1;

    lvs[tid] = inb[(size_t)last_idx * Dn + tid];
    __syncthreads();

    float q = 0.f;
    #pragma unroll 16
    for (int d = 0; d < Dn; ++d) q = fmaf(lvs[d], Wt[d * Hn + tid], q);
    qs[tid] = q;
    __syncthreads();

    float u = 0.f;
    const float* wxr = Wx + tid * Hn;
    #pragma unroll 16
    for (int h = 0; h < Hn; ++h) u = fmaf(wxr[h], qs[h], u);
    ws_u[b * Dn + tid] = u;
}

// ---------------- K2: half-batch pure stream ----------------
constexpr int NT2 = 512;
constexpr int NW2 = NT2 / 64;
constexpr int HR  = Tn / 2;          // 256 rows per block
constexpr int SW  = HR / 32;         // 8 sweeps of 32 rows

__global__ __launch_bounds__(NT2, 4)   // VGPR<=128, proven spill-free regime
void attn_stream2(const float* __restrict__ input,   // [B,T,D]
                  const int*   __restrict__ mask,    // [B,T]
                  const float* __restrict__ ws_u,    // [B,D]
                  const float* __restrict__ rate,    // [1]
                  float* __restrict__ vpart,         // [2B, D]
                  float* __restrict__ lpart,         // [2B]
                  float* __restrict__ out_a)         // [B,T] (unnormalized p)
{
    const int j    = blockIdx.x;
    const int b    = j >> 1;
    const int half = j & 1;
    const int tid  = threadIdx.x;
    const int lane = tid & 63;
    const int wid  = tid >> 6;
    const int seg  = tid & 15;     // 16 lanes per row; floats seg*8..seg*8+7
    const int rg   = tid >> 4;     // row group 0..31
    const int rbase = half * HR;
    const float4* __restrict__ in4 = (const float4*)(input + (size_t)b * Tn * Dn);

    __shared__ int   msk[HR];          // 1 KB
    __shared__ float redl[NW2];
    __shared__ float vp[32 * 132];     // 16.9 KB v partials

    if (tid < HR) msk[tid] = mask[(size_t)b * Tn + rbase + tid];
    const float4 u4a = ((const float4*)(ws_u + b * Dn))[seg * 2];
    const float4 u4b = ((const float4*)(ws_u + b * Dn))[seg * 2 + 1];
    const float srate = 1.f / (1.f + __expf(-rate[0]));
    __syncthreads();

    // e = relu(sig/den) in [0, ~1.45] (den >= sigmoid(0.8)*log(2.72) ~= 0.69),
    // so exp(e) <= 4.3: softmax needs no max subtraction.
    float4 v0 = make_float4(0.f, 0.f, 0.f, 0.f);
    float4 v1 = make_float4(0.f, 0.f, 0.f, 0.f);
    float  lsum = 0.f;

    #pragma unroll
    for (int s = 0; s < SW; ++s) {
        const int rl  = s * 32 + rg;           // local row 0..255
        const int row = rbase + rl;            // global t
        const float4 x0 = in4[row * 32 + seg * 2];
        const float4 x1 = in4[row * 32 + seg * 2 + 1];
        float dot = x0.x * u4a.x + x0.y * u4a.y + x0.z * u4a.z + x0.w * u4a.w;
        dot = fmaf(x1.x, u4b.x, dot);
        dot = fmaf(x1.y, u4b.y, dot);
        dot = fmaf(x1.z, u4b.z, dot);
        dot = fmaf(x1.w, u4b.w, dot);
        dot = rowsum16(dot);                   // DPP reduce: no DS ops
        const float sig = 1.f / (1.f + __expf(-dot));
        const float den = srate * (__logf(2.72f + (1.f - sig)) * (float)(Tn - row));
        const float e   = fmaxf(sig / den, 0.f);
        const float p   = msk[rl] ? __expf(e) : 0.f;
        v0.x = fmaf(p, x0.x, v0.x);
        v0.y = fmaf(p, x0.y, v0.y);
        v0.z = fmaf(p, x0.z, v0.z);
        v0.w = fmaf(p, x0.w, v0.w);
        v1.x = fmaf(p, x1.x, v1.x);
        v1.y = fmaf(p, x1.y, v1.y);
        v1.z = fmaf(p, x1.z, v1.z);
        v1.w = fmaf(p, x1.w, v1.w);
        if (seg == 0) { out_a[(size_t)b * Tn + row] = p; lsum += p; }
    }

    // stash v partials (16B-aligned: rg*132 + seg*8)
    {
        float* vr = vp + rg * 132 + seg * 8;
        ((float4*)vr)[0] = v0;
        ((float4*)vr)[1] = v1;
    }
    // block-reduce l (nonzero only on seg==0 lanes)
    float ls = lsum;
    #pragma unroll
    for (int off = 32; off > 0; off >>= 1) ls += __shfl_down(ls, off, 64);
    if (lane == 0) redl[wid] = ls;
    __syncthreads();   // vp + redl visible

    if (tid < Dn) {
        float s = 0.f;
        #pragma unroll
        for (int r = 0; r < 32; ++r) s += vp[r * 132 + tid];
        vpart[(size_t)j * Dn + tid] = s;
    }
    if (tid == 0) {
        float l = 0.f;
        #pragma unroll
        for (int w = 0; w < NW2; ++w) l += redl[w];
        lpart[j] = l;
    }
}

// ---------------- K3: finish (normalize a, combine v halves) ----------------
__global__ __launch_bounds__(512)
void attn_finish(const float* __restrict__ vpart,   // [2B, D]
                 const float* __restrict__ lpart,   // [2B]
                 float* __restrict__ out_v,         // [B,D]
                 float* __restrict__ out_a)         // [B,T]
{
    const int b   = blockIdx.x;
    const int tid = threadIdx.x;
    const float invl = 1.f / (lpart[2 * b] + lpart[2 * b + 1]);
    out_a[(size_t)b * Tn + tid] *= invl;
    if (tid < Dn)
        out_v[(size_t)b * Dn + tid] =
            (vpart[(size_t)(2 * b) * Dn + tid] + vpart[(size_t)(2 * b + 1) * Dn + tid]) * invl;
}

extern "C" void kernel_launch(void* const* d_in, const int* in_sizes, int n_in,
                              void* d_out, int out_size, void* d_ws, size_t ws_size,
                              hipStream_t stream) {
    const float* input = (const float*)d_in[0];   // [B,T,D]
    const int*   mask  = (const int*)d_in[1];     // [B,T]
    const float* Wt    = (const float*)d_in[2];   // [D,H]
    const float* Wx    = (const float*)d_in[3];   // [D,H]
    const float* rate  = (const float*)d_in[4];   // [1]

    float* out   = (float*)d_out;
    float* out_v = out;                 // [B,D]  (return order: v, a)
    float* out_a = out + Bn * Dn;       // [B,T]

    float* ws_u  = (float*)d_ws;                  // [B,D]
    float* vpart = ws_u + (size_t)Bn * Dn;        // [2B,D]
    float* lpart = vpart + (size_t)2 * Bn * Dn;   // [2B]

    compute_u_kernel<<<Bn, 128, 0, stream>>>(input, mask, Wt, Wx, ws_u);
    attn_stream2<<<2 * Bn, NT2, 0, stream>>>(input, mask, ws_u, rate, vpart, lpart, out_a);
    attn_finish<<<Bn, 512, 0, stream>>>(vpart, lpart, out_v, out_a);
}